// Round 1
// 362.907 us; speedup vs baseline: 1.0480x; 1.0480x over previous
//
#include <hip/hip_runtime.h>

#define T_TOK 16384
#define E_EXP 16
#define CAP   2048
#define D_DIM 2048
#define NCHUNK (T_TOK / 256)   // 64 chunks of 256 tokens
#define NZERO  128             // tail-zeroing blocks (8 per expert)

typedef float vf4 __attribute__((ext_vector_type(4)));

// ---------- K1: per-chunk per-expert counts (64 blocks x 256 thr) ----------
__global__ __launch_bounds__(256) void count_kernel(
    const int* __restrict__ hot_mask,   // [T, E]
    int*       __restrict__ counts)     // [NCHUNK, E]
{
    const int chunk = blockIdx.x;
    const int tid   = threadIdx.x;
    const int t     = chunk * 256 + tid;
    const int lane  = tid & 63;
    const int wv    = tid >> 6;

    const int4* row = (const int4*)(hot_mask + (size_t)t * E_EXP);
    int4 r0 = row[0], r1 = row[1], r2 = row[2], r3 = row[3];
    int hm[16] = { r0.x > 0, r0.y > 0, r0.z > 0, r0.w > 0,
                   r1.x > 0, r1.y > 0, r1.z > 0, r1.w > 0,
                   r2.x > 0, r2.y > 0, r2.z > 0, r2.w > 0,
                   r3.x > 0, r3.y > 0, r3.z > 0, r3.w > 0 };

    __shared__ int wcnt[4][16];
    #pragma unroll
    for (int e = 0; e < 16; ++e) {
        unsigned long long m = __ballot(hm[e]);
        if (lane == 0) wcnt[wv][e] = __popcll(m);
    }
    __syncthreads();
    if (tid < 16)
        counts[chunk * E_EXP + tid] =
            wcnt[0][tid] + wcnt[1][tid] + wcnt[2][tid] + wcnt[3][tid];
}

// ---------- K2: fused scan + fill (64 blocks x 256 thr) --------------------
// Each block recomputes its chunk's exclusive per-expert offset from the 4 KB
// counts matrix (removes the separate scan kernel), then emits PER-TOKEN
// destination slots + gates (token-driven layout for the gather).
__global__ __launch_bounds__(256) void scanfill_kernel(
    const int*   __restrict__ hot_mask,
    const float* __restrict__ score,
    const int*   __restrict__ counts,     // [NCHUNK, E]
    int*         __restrict__ dst2,       // [T, 2] slot index or -1
    float*       __restrict__ g2,         // [T, 2]
    int*         __restrict__ loads_i,    // [E]
    float*       __restrict__ loads_out)  // [E] float (d_out tail)
{
    const int chunk = blockIdx.x;
    const int tid   = threadIdx.x;
    const int t     = chunk * 256 + tid;
    const int lane  = tid & 63;
    const int wv    = tid >> 6;

    __shared__ int s_off[16];      // exclusive chunk offset per expert
    __shared__ int wcnt[4][16];

    if (tid < 16) {
        const int e = tid;
        int off = 0, tot = 0;
        #pragma unroll 8
        for (int c = 0; c < NCHUNK; ++c) {
            const int v = counts[c * E_EXP + e];
            off += (c < chunk) ? v : 0;
            tot += v;
        }
        s_off[e] = off;
        if (chunk == 0) {
            const int ld = tot < CAP ? tot : CAP;
            loads_i[e]   = ld;
            loads_out[e] = (float)ld;
        }
    }

    const int4* mrow = (const int4*)(hot_mask + (size_t)t * E_EXP);
    int4 r0 = mrow[0], r1 = mrow[1], r2 = mrow[2], r3 = mrow[3];
    int hm[16] = { r0.x > 0, r0.y > 0, r0.z > 0, r0.w > 0,
                   r1.x > 0, r1.y > 0, r1.z > 0, r1.w > 0,
                   r2.x > 0, r2.y > 0, r2.z > 0, r2.w > 0,
                   r3.x > 0, r3.y > 0, r3.z > 0, r3.w > 0 };

    const float4* srow = (const float4*)(score + (size_t)t * E_EXP);
    float4 s0 = srow[0], s1 = srow[1], s2 = srow[2], s3 = srow[3];
    float sc[16] = { s0.x, s0.y, s0.z, s0.w, s1.x, s1.y, s1.z, s1.w,
                     s2.x, s2.y, s2.z, s2.w, s3.x, s3.y, s3.z, s3.w };

    int before[16];
    const unsigned long long lmask = (1ULL << lane) - 1ULL;
    #pragma unroll
    for (int e = 0; e < 16; ++e) {
        unsigned long long m = __ballot(hm[e]);
        before[e] = __popcll(m & lmask);
        if (lane == 0) wcnt[wv][e] = __popcll(m);
    }
    __syncthreads();

    // token order preserved: chunk-major, then wave, then lane (same as before)
    int   d0 = -1, d1 = -1;
    float gg0 = 0.f, gg1 = 0.f;
    int   k = 0;
    #pragma unroll
    for (int e = 0; e < 16; ++e) {
        if (hm[e]) {
            int woff = 0;
            for (int w = 0; w < 4; ++w) if (w < wv) woff += wcnt[w][e];
            const int pos  = s_off[e] + woff + before[e];
            const int slot = (pos < CAP) ? e * CAP + pos : -1;  // -1 = dropped
            if (k == 0)      { d0 = slot; gg0 = sc[e]; }
            else if (k == 1) { d1 = slot; gg1 = sc[e]; }
            ++k;
        }
    }
    ((int2*)dst2)[t]  = make_int2(d0, d1);
    ((float2*)g2)[t]  = make_float2(gg0, gg1);
}

// ---------- K3: token-driven gather + tail zero (128 + T blocks) -----------
// Each token's row is read from HBM exactly ONCE (NT load), scaled, and
// NT-stored to its <=2 destination slots. Blocks 0..127 zero the invalid
// tail slots [load_e, CAP) per expert (disjoint from valid slots).
__global__ __launch_bounds__(256) void gather_kernel(
    const float* __restrict__ in_flow,
    const int*   __restrict__ dst2,
    const float* __restrict__ g2,
    const int*   __restrict__ loads_i,
    float*       __restrict__ out)
{
    const int b   = blockIdx.x;
    const int tid = threadIdx.x;

    if (b < NZERO) {
        const int e = b >> 3, p = b & 7;
        const int ld = loads_i[e];
        const vf4 z = {0.f, 0.f, 0.f, 0.f};
        for (int s = ld + p; s < CAP; s += 8) {
            vf4* o = (vf4*)(out + ((size_t)e * CAP + s) * D_DIM);
            __builtin_nontemporal_store(z, o + tid);
            __builtin_nontemporal_store(z, o + tid + 256);
        }
        return;
    }

    const int t  = b - NZERO;
    const int d0 = dst2[2 * t];
    const int d1 = dst2[2 * t + 1];
    if (d0 < 0 && d1 < 0) return;   // token fully dropped: skip the read

    const vf4* irow = (const vf4*)(in_flow + (size_t)t * D_DIM);
    vf4 v0 = __builtin_nontemporal_load(irow + tid);
    vf4 v1 = __builtin_nontemporal_load(irow + tid + 256);

    if (d0 >= 0) {
        const float g = g2[2 * t];
        vf4* o = (vf4*)(out + (size_t)d0 * D_DIM);
        __builtin_nontemporal_store(v0 * g, o + tid);
        __builtin_nontemporal_store(v1 * g, o + tid + 256);
    }
    if (d1 >= 0) {
        const float g = g2[2 * t + 1];
        vf4* o = (vf4*)(out + (size_t)d1 * D_DIM);
        __builtin_nontemporal_store(v0 * g, o + tid);
        __builtin_nontemporal_store(v1 * g, o + tid + 256);
    }
}

extern "C" void kernel_launch(void* const* d_in, const int* in_sizes, int n_in,
                              void* d_out, int out_size, void* d_ws, size_t ws_size,
                              hipStream_t stream) {
    const float* in_flow  = (const float*)d_in[0];
    const int*   hot_mask = (const int*)d_in[1];
    const float* score    = (const float*)d_in[2];

    float* out       = (float*)d_out;
    float* loads_out = out + (size_t)E_EXP * CAP * D_DIM;

    char* ws = (char*)d_ws;
    int*   counts  = (int*)ws;   ws += NCHUNK * E_EXP * sizeof(int);
    int*   loads_i = (int*)ws;   ws += 64 * sizeof(int);
    int*   dst2    = (int*)ws;   ws += (size_t)T_TOK * 2 * sizeof(int);
    float* g2      = (float*)ws;

    count_kernel<<<NCHUNK, 256, 0, stream>>>(hot_mask, counts);
    scanfill_kernel<<<NCHUNK, 256, 0, stream>>>(hot_mask, score, counts,
                                                dst2, g2, loads_i, loads_out);
    gather_kernel<<<T_TOK + NZERO, 256, 0, stream>>>(in_flow, dst2, g2,
                                                     loads_i, out);
}